// Round 3
// baseline (518.863 us; speedup 1.0000x reference)
//
#include <hip/hip_runtime.h>

// NodeLevelSet: P2G mass-weighted gradient scatter (masked to selected nodes)
// + per-node friction update + scatter-set into grid moment field.
//
// Inputs (f32 unless noted):
//  0 mass_stack        [Np]
//  1 shapef_grad_stack [Np, W, 3]
//  2 cnode_ids         [Np, W]  int32
//  3 node_moment_nt    [NC, 3]
//  4 node_mass         [NC]
//  5 id_stack          [NS]     int32 (unique)
//  6 velocity_stack    [NS, 3]
// Output: node_moment_nt with rows id_stack replaced. [NC,3] f32.

#define MU_F 0.5f
#define SMALL_MASS_CUTOFF 1e-10f

// ---- K1: set bitmask bits for selected nodes; zero their accumulator rows.
__global__ void build_mask_kernel(const int* __restrict__ id_stack, int ns,
                                  unsigned int* __restrict__ mask,
                                  float* __restrict__ acc) {
    int i = blockIdx.x * blockDim.x + threadIdx.x;
    if (i >= ns) return;
    int id = id_stack[i];
    atomicOr(&mask[id >> 5], 1u << (id & 31));
    size_t b = (size_t)id * 3;
    acc[b + 0] = 0.0f;
    acc[b + 1] = 0.0f;
    acc[b + 2] = 0.0f;
}

// ---- K2: masked P2G scatter. One thread per (particle, stencil-node) pair.
// LOG2W: log2 of stencil width (W=8 -> 3).
template <int LOG2W>
__global__ void p2g_kernel(const float* __restrict__ mass_stack,
                           const float* __restrict__ grad,   // [Np*W, 3]
                           const int*   __restrict__ ids,    // [Np*W]
                           const unsigned int* __restrict__ mask,
                           float* __restrict__ acc,          // [NC, 3]
                           int npairs) {
    int pair = blockIdx.x * blockDim.x + threadIdx.x;
    if (pair >= npairs) return;
    int id = ids[pair];                       // coalesced 4B/lane
    unsigned int w = mask[(unsigned)id >> 5]; // 256KB table, L1/L2-hot
    if (w & (1u << (id & 31))) {
        float m = mass_stack[pair >> LOG2W];  // broadcast within 8-lane groups
        const float* g = grad + (size_t)pair * 3;
        float gx = g[0], gy = g[1], gz = g[2];
        size_t b = (size_t)id * 3;
        unsafeAtomicAdd(&acc[b + 0], gx * m);
        unsafeAtomicAdd(&acc[b + 1], gy * m);
        unsafeAtomicAdd(&acc[b + 2], gz * m);
    }
}

// Generic-W fallback (not used for W=8 but keeps correctness for any layout).
__global__ void p2g_kernel_generic(const float* __restrict__ mass_stack,
                                   const float* __restrict__ grad,
                                   const int*   __restrict__ ids,
                                   const unsigned int* __restrict__ mask,
                                   float* __restrict__ acc,
                                   int npairs, int W) {
    int pair = blockIdx.x * blockDim.x + threadIdx.x;
    if (pair >= npairs) return;
    int id = ids[pair];
    unsigned int w = mask[(unsigned)id >> 5];
    if (w & (1u << (id & 31))) {
        float m = mass_stack[pair / W];
        const float* g = grad + (size_t)pair * 3;
        size_t b = (size_t)id * 3;
        unsafeAtomicAdd(&acc[b + 0], g[0] * m);
        unsafeAtomicAdd(&acc[b + 1], g[1] * m);
        unsafeAtomicAdd(&acc[b + 2], g[2] * m);
    }
}

// ---- K3: friction update for selected nodes; overwrite output rows.
__global__ void friction_kernel(const int*   __restrict__ id_stack,
                                const float* __restrict__ velocity,   // [NS,3]
                                const float* __restrict__ node_mass,  // [NC]
                                const float* __restrict__ node_moment,// [NC,3]
                                const float* __restrict__ acc,        // [NC,3]
                                float* __restrict__ out,              // [NC,3]
                                int ns) {
    int i = blockIdx.x * blockDim.x + threadIdx.x;
    if (i >= ns) return;
    int id = id_stack[i];
    size_t b = (size_t)id * 3;

    float nx = acc[b + 0], ny = acc[b + 1], nz = acc[b + 2];
    float mass = node_mass[id];
    float mx = node_moment[b + 0], my = node_moment[b + 1], mz = node_moment[b + 2];

    bool valid = mass > SMALL_MASS_CUTOFF;
    float inv_mass = valid ? 1.0f / mass : 0.0f;
    float vx = mx * inv_mass, vy = my * inv_mass, vz = mz * inv_mass;

    float nn = sqrtf(nx * nx + ny * ny + nz * nz);
    bool ok = valid && (nn > 0.0f);
    float hx = 0.0f, hy = 0.0f, hz = 0.0f;
    if (ok) { float r = 1.0f / nn; hx = nx * r; hy = ny * r; hz = nz * r; }

    size_t vb = (size_t)i * 3;
    float dvx = vx - velocity[vb + 0];
    float dvy = vy - velocity[vb + 1];
    float dvz = vz - velocity[vb + 2];
    float dvn = dvx * hx + dvy * hy + dvz * hz;

    float ox = vx, oy = vy, oz = vz;   // default: no friction applied
    if (dvn > 0.0f) {
        // cross = delta_vel x normal_hat
        float cx = dvy * hz - dvz * hy;
        float cy = dvz * hx - dvx * hz;
        float cz = dvx * hy - dvy * hx;
        float cn = sqrtf(cx * cx + cy * cy + cz * cz);
        float wx = 0.0f, wy = 0.0f, wz = 0.0f;
        if (cn > 0.0f) { float r = 1.0f / cn; wx = cx * r; wy = cy * r; wz = cz * r; }
        float mu_p = fminf(MU_F, cn / dvn);   // dvn > 0 here, matches reference
        // tangent = normal_hat + mu_p * cross(normal_hat, omega)
        float tx = hx + mu_p * (hy * wz - hz * wy);
        float ty = hy + mu_p * (hz * wx - hx * wz);
        float tz = hz + mu_p * (hx * wy - hy * wx);
        ox = vx - dvn * tx;
        oy = vy - dvn * ty;
        oz = vz - dvn * tz;
    }
    out[b + 0] = ox * mass;
    out[b + 1] = oy * mass;
    out[b + 2] = oz * mass;
}

extern "C" void kernel_launch(void* const* d_in, const int* in_sizes, int n_in,
                              void* d_out, int out_size, void* d_ws, size_t ws_size,
                              hipStream_t stream) {
    const float* mass_stack  = (const float*)d_in[0];
    const float* grad        = (const float*)d_in[1];
    const int*   cnode_ids   = (const int*)d_in[2];
    const float* node_moment = (const float*)d_in[3];
    const float* node_mass   = (const float*)d_in[4];
    const int*   id_stack    = (const int*)d_in[5];
    const float* velocity    = (const float*)d_in[6];
    float* out = (float*)d_out;

    const int np     = in_sizes[0];
    const int npairs = in_sizes[2];       // Np * W
    const int nc     = in_sizes[4];
    const int ns     = in_sizes[5];
    const int W      = npairs / np;

    // workspace layout: acc [nc*3] f32, then mask [ceil(nc/32)] u32
    float* acc = (float*)d_ws;
    unsigned int* mask = (unsigned int*)(acc + (size_t)nc * 3);
    const size_t mask_words = (size_t)(nc + 31) / 32;

    (void)hipMemsetAsync(mask, 0, mask_words * sizeof(unsigned int), stream);

    build_mask_kernel<<<(ns + 255) / 256, 256, 0, stream>>>(id_stack, ns, mask, acc);

    const int blocks = (npairs + 255) / 256;
    if (W == 8) {
        p2g_kernel<3><<<blocks, 256, 0, stream>>>(mass_stack, grad, cnode_ids,
                                                  mask, acc, npairs);
    } else if (W == 4) {
        p2g_kernel<2><<<blocks, 256, 0, stream>>>(mass_stack, grad, cnode_ids,
                                                  mask, acc, npairs);
    } else {
        p2g_kernel_generic<<<blocks, 256, 0, stream>>>(mass_stack, grad, cnode_ids,
                                                       mask, acc, npairs, W);
    }

    // Bulk copy of the unmodified moment field into the output.
    (void)hipMemcpyAsync(out, node_moment, (size_t)out_size * sizeof(float),
                         hipMemcpyDeviceToDevice, stream);

    friction_kernel<<<(ns + 255) / 256, 256, 0, stream>>>(id_stack, velocity,
                                                          node_mass, node_moment,
                                                          acc, out, ns);
}

// Round 4
// 460.511 us; speedup vs baseline: 1.1267x; 1.1267x over previous
//
#include <hip/hip_runtime.h>

// NodeLevelSet: masked P2G scatter with packed fixed-point u64 atomics
// + fused copy/friction epilogue (replaces slow in-graph SDMA memcpy).
//
// Fixed-point packing (per hit, 2 atomics instead of 3):
//   accA = [y_lane:32][x_lane:32]          lane = round(v*2^20) + 2^24
//   accB = [i:24][count:8][z_lane:32]      each hit adds (1<<32) | z_lane
// Lanes stay positive (bias 2^24 > max |v|*2^20 for |v|<~14), so no carries
// cross lanes for up to ~128 contributions/node (actual avg ~7.6).
// Decode: v = (lane - count*2^24) * 2^-20.  Quantization ~1e-6 per hit.

#define MU_F 0.5f
#define SMALL_MASS_CUTOFF 1e-10f

#define FP_SCALE 1048576.0f              // 2^20
#define FP_INV   9.5367431640625e-07f    // 2^-20
#define FP_BIAS  (1 << 24)

typedef unsigned long long u64;
typedef unsigned int u32;

// ---- K1: mask bits + init acc records (+ inv map in compact mode)
template <bool COMPACT>
__global__ void build_mask_kernel(const int* __restrict__ id_stack, int ns,
                                  u32* __restrict__ mask,
                                  u64* __restrict__ acc,
                                  u32* __restrict__ inv) {
    int i = blockIdx.x * blockDim.x + threadIdx.x;
    if (i >= ns) return;
    int id = id_stack[i];
    atomicOr(&mask[(u32)id >> 5], 1u << (id & 31));
    size_t slot = COMPACT ? (size_t)i : (size_t)id;
    if (COMPACT) inv[id] = (u32)i;
    acc[2 * slot]     = 0ull;
    acc[2 * slot + 1] = (u64)(u32)i << 40;   // i field; count/z lanes zero
}

// ---- K2: masked P2G. One thread per (particle, stencil-node) pair.
template <int LOG2W, bool COMPACT>
__global__ void p2g_kernel(const float* __restrict__ mass_stack,
                           const float* __restrict__ grad,   // [Np*W, 3]
                           const int*   __restrict__ ids,    // [Np*W]
                           const u32*   __restrict__ mask,
                           const u32*   __restrict__ inv,
                           u64* __restrict__ acc,
                           int npairs, int W) {
    int pair = blockIdx.x * blockDim.x + threadIdx.x;
    if (pair >= npairs) return;
    int id = ids[pair];                         // coalesced 4B/lane
    u32 mword = mask[(u32)id >> 5];             // 256KB table, L2-hot
    if (mword & (1u << (id & 31))) {
        int pidx = (LOG2W > 0) ? (pair >> LOG2W) : (pair / W);
        float m = mass_stack[pidx];
        const float* g = grad + (size_t)pair * 3;
        int xi = __float2int_rn(g[0] * m * FP_SCALE);
        int yi = __float2int_rn(g[1] * m * FP_SCALE);
        int zi = __float2int_rn(g[2] * m * FP_SCALE);
        u64 a = ((u64)(u32)(yi + FP_BIAS) << 32) | (u32)(xi + FP_BIAS);
        u64 b = (1ull << 32) | (u32)(zi + FP_BIAS);
        size_t slot = COMPACT ? (size_t)inv[id] : (size_t)id;
        atomicAdd(&acc[2 * slot], a);
        atomicAdd(&acc[2 * slot + 1], b);
    }
}

// ---- K3: fused epilogue over ALL nc nodes: copy-through or friction update.
template <bool COMPACT>
__global__ void epilogue_kernel(const float* __restrict__ node_moment, // [NC,3]
                                const u32*   __restrict__ mask,
                                const u32*   __restrict__ inv,
                                const u64*   __restrict__ acc,
                                const float* __restrict__ node_mass,   // [NC]
                                const float* __restrict__ velocity,    // [NS,3]
                                float* __restrict__ out,               // [NC,3]
                                int nc) {
    int c = blockIdx.x * blockDim.x + threadIdx.x;
    if (c >= nc) return;
    size_t b3 = (size_t)c * 3;
    float mx = node_moment[b3 + 0];
    float my = node_moment[b3 + 1];
    float mz = node_moment[b3 + 2];

    u32 mword = mask[(u32)c >> 5];
    if (!(mword & (1u << (c & 31)))) {          // untouched node: pass through
        out[b3 + 0] = mx; out[b3 + 1] = my; out[b3 + 2] = mz;
        return;
    }

    size_t slot = COMPACT ? (size_t)inv[c] : (size_t)c;
    u64 a  = acc[2 * slot];
    u64 bb = acc[2 * slot + 1];
    u32 cnt = (u32)(bb >> 32) & 0xFFu;
    int i   = (int)(bb >> 40);
    long long bias = (long long)cnt * (long long)FP_BIAS;
    float nx = (float)((long long)(a & 0xFFFFFFFFull) - bias) * FP_INV;
    float ny = (float)((long long)(a >> 32) - bias) * FP_INV;
    float nz = (float)((long long)(bb & 0xFFFFFFFFull) - bias) * FP_INV;

    float mass = node_mass[c];
    bool valid = mass > SMALL_MASS_CUTOFF;
    float inv_mass = valid ? 1.0f / mass : 0.0f;
    float vx = mx * inv_mass, vy = my * inv_mass, vz = mz * inv_mass;

    float nn = sqrtf(nx * nx + ny * ny + nz * nz);
    bool ok = valid && (nn > 0.0f);
    float hx = 0.0f, hy = 0.0f, hz = 0.0f;
    if (ok) { float r = 1.0f / nn; hx = nx * r; hy = ny * r; hz = nz * r; }

    size_t vb = (size_t)i * 3;
    float dvx = vx - velocity[vb + 0];
    float dvy = vy - velocity[vb + 1];
    float dvz = vz - velocity[vb + 2];
    float dvn = dvx * hx + dvy * hy + dvz * hz;

    float ox = vx, oy = vy, oz = vz;
    if (dvn > 0.0f) {
        float cx = dvy * hz - dvz * hy;
        float cy = dvz * hx - dvx * hz;
        float cz = dvx * hy - dvy * hx;
        float cn = sqrtf(cx * cx + cy * cy + cz * cz);
        float wx = 0.0f, wy = 0.0f, wz = 0.0f;
        if (cn > 0.0f) { float r = 1.0f / cn; wx = cx * r; wy = cy * r; wz = cz * r; }
        float mu_p = fminf(MU_F, cn / dvn);
        float tx = hx + mu_p * (hy * wz - hz * wy);
        float ty = hy + mu_p * (hz * wx - hx * wz);
        float tz = hz + mu_p * (hx * wy - hy * wx);
        ox = vx - dvn * tx;
        oy = vy - dvn * ty;
        oz = vz - dvn * tz;
    }
    out[b3 + 0] = ox * mass;
    out[b3 + 1] = oy * mass;
    out[b3 + 2] = oz * mass;
}

extern "C" void kernel_launch(void* const* d_in, const int* in_sizes, int n_in,
                              void* d_out, int out_size, void* d_ws, size_t ws_size,
                              hipStream_t stream) {
    const float* mass_stack  = (const float*)d_in[0];
    const float* grad        = (const float*)d_in[1];
    const int*   cnode_ids   = (const int*)d_in[2];
    const float* node_moment = (const float*)d_in[3];
    const float* node_mass   = (const float*)d_in[4];
    const int*   id_stack    = (const int*)d_in[5];
    const float* velocity    = (const float*)d_in[6];
    float* out = (float*)d_out;

    const int np     = in_sizes[0];
    const int npairs = in_sizes[2];       // Np * W
    const int nc     = in_sizes[4];
    const int ns     = in_sizes[5];
    const int W      = npairs / np;

    const size_t mask_words = (size_t)(nc + 31) / 32;

    // Primary ws layout (acc indexed by node id): acc u64[2*nc], mask u32.
    // Compact fallback (acc indexed by compact i): acc u64[2*ns], inv u32[nc], mask.
    const size_t need_full    = (size_t)nc * 16 + mask_words * 4;
    const bool   compact      = ws_size < need_full;

    u64* acc;
    u32* inv;
    u32* mask;
    if (!compact) {
        acc  = (u64*)d_ws;
        mask = (u32*)(acc + 2 * (size_t)nc);
        inv  = nullptr;
    } else {
        acc  = (u64*)d_ws;
        inv  = (u32*)(acc + 2 * (size_t)ns);
        mask = inv + (size_t)nc;
    }

    (void)hipMemsetAsync(mask, 0, mask_words * 4, stream);

    const int mb = (ns + 255) / 256;
    const int pb = (npairs + 255) / 256;
    const int eb = (nc + 255) / 256;

    if (!compact) {
        build_mask_kernel<false><<<mb, 256, 0, stream>>>(id_stack, ns, mask, acc, inv);
        if (W == 8)
            p2g_kernel<3, false><<<pb, 256, 0, stream>>>(mass_stack, grad, cnode_ids,
                                                         mask, inv, acc, npairs, W);
        else if (W == 4)
            p2g_kernel<2, false><<<pb, 256, 0, stream>>>(mass_stack, grad, cnode_ids,
                                                         mask, inv, acc, npairs, W);
        else
            p2g_kernel<0, false><<<pb, 256, 0, stream>>>(mass_stack, grad, cnode_ids,
                                                         mask, inv, acc, npairs, W);
        epilogue_kernel<false><<<eb, 256, 0, stream>>>(node_moment, mask, inv, acc,
                                                       node_mass, velocity, out, nc);
    } else {
        build_mask_kernel<true><<<mb, 256, 0, stream>>>(id_stack, ns, mask, acc, inv);
        if (W == 8)
            p2g_kernel<3, true><<<pb, 256, 0, stream>>>(mass_stack, grad, cnode_ids,
                                                        mask, inv, acc, npairs, W);
        else if (W == 4)
            p2g_kernel<2, true><<<pb, 256, 0, stream>>>(mass_stack, grad, cnode_ids,
                                                        mask, inv, acc, npairs, W);
        else
            p2g_kernel<0, true><<<pb, 256, 0, stream>>>(mass_stack, grad, cnode_ids,
                                                        mask, inv, acc, npairs, W);
        epilogue_kernel<true><<<eb, 256, 0, stream>>>(node_moment, mask, inv, acc,
                                                      node_mass, velocity, out, nc);
    }
}